// Round 8
// baseline (112.475 us; speedup 1.0000x reference)
//
#include <hip/hip_runtime.h>

// DmelsQuantizer: idx = argmin_k |x - codebook[k]|, first-min tie-breaking.
// Sorted uniform codebook => idx = #{midpoints strictly below x} (strict '>'
// reproduces argmin's pick-first-on-tie rule). Verified bit-exact (r6 absmax=0).
// Output is int32 (harness reads np.int32).
//
// r6 evidence: dur_us=109.4 includes harness resets (256MiB d_ws poison = 41us
// fills dominate top-5; our kernel < 40.8us). Kernel-side floor ~19.5us
// (61MB read + 61MB write @ 6.3TB/s). This round: one-shot exact launch
// (n4 = 15000*256 exactly) + nontemporal vector ld/st.

typedef float f32x4 __attribute__((ext_vector_type(4)));
typedef int   i32x4 __attribute__((ext_vector_type(4)));

__global__ __launch_bounds__(256) void dmels_quant_kernel(
    const float* __restrict__ x,
    const float* __restrict__ cb,
    int* __restrict__ out,
    int n4, int n) {
  // Codebook: 16 wave-uniform loads once per thread, then 15 midpoints in VGPRs.
  float mid[15];
#pragma unroll
  for (int k = 0; k < 15; ++k) mid[k] = 0.5f * (cb[k] + cb[k + 1]);

  const int gid = blockIdx.x * blockDim.x + threadIdx.x;

  const f32x4* __restrict__ x4 = (const f32x4*)x;
  i32x4* __restrict__ o4 = (i32x4*)out;

  if (gid < n4) {
    f32x4 v = __builtin_nontemporal_load(x4 + gid);
    int c0 = 0, c1 = 0, c2 = 0, c3 = 0;
#pragma unroll
    for (int k = 0; k < 15; ++k) {
      c0 += (v.x > mid[k]);
      c1 += (v.y > mid[k]);
      c2 += (v.z > mid[k]);
      c3 += (v.w > mid[k]);
    }
    i32x4 r;
    r.x = c0; r.y = c1; r.z = c2; r.w = c3;
    __builtin_nontemporal_store(r, o4 + gid);
  }

  // Scalar tail (n % 4) — n=15,360,000 is divisible by 4; kept for safety.
  const int total = gridDim.x * blockDim.x;
  for (int j = n4 * 4 + gid; j < n; j += total) {
    float v = x[j];
    int c = 0;
#pragma unroll
    for (int k = 0; k < 15; ++k) c += (v > mid[k]);
    out[j] = c;
  }
}

extern "C" void kernel_launch(void* const* d_in, const int* in_sizes, int n_in,
                              void* d_out, int out_size, void* d_ws, size_t ws_size,
                              hipStream_t stream) {
  const float* x = (const float*)d_in[0];
  const float* cb = (const float*)d_in[1];
  int* out = (int*)d_out;

  const int n = in_sizes[0];
  const int n4 = n / 4;

  const int block = 256;
  int grid = (n4 + block - 1) / block;  // 15000 for n=15,360,000 — one shot
  if (grid < 1) grid = 1;

  dmels_quant_kernel<<<grid, block, 0, stream>>>(x, cb, out, n4, n);
}

// Round 9
// 107.530 us; speedup vs baseline: 1.0460x; 1.0460x over previous
//
#include <hip/hip_runtime.h>

// DmelsQuantizer: idx = argmin_k |x - codebook[k]|, first-min tie-breaking.
// Sorted uniform codebook => idx = #{midpoints strictly below x} (strict '>'
// reproduces argmin's pick-first-on-tie rule). Verified bit-exact (r6/r8 absmax=0).
// Output is int32 (harness reads np.int32).
//
// Evidence ledger:
//  r6: grid-stride + cached ld/st            -> 109.4 us
//  r8: one-shot + NT load + NT store         -> 112.5 us (neutral/noise)
//  Top-5 dispatches are harness fills (256MiB d_ws poison ~42us each);
//  fixed harness resets ~71us/iter. Kernel floor ~19.5us (123MB @ 6.3TB/s),
//  less if warm-L3 input reuse is captured.
//  r9 change (single variable vs r8): CACHED load (x is L3-warm from the
//  harness's input-restore copy each iter; NT load discards that reuse).
//  NT store kept (output never re-read; keeps L2/L3 free for x).

typedef float f32x4 __attribute__((ext_vector_type(4)));
typedef int   i32x4 __attribute__((ext_vector_type(4)));

__global__ __launch_bounds__(256) void dmels_quant_kernel(
    const float* __restrict__ x,
    const float* __restrict__ cb,
    int* __restrict__ out,
    int n4, int n) {
  // Codebook: 16 wave-uniform loads once per thread, then 15 midpoints in VGPRs.
  float mid[15];
#pragma unroll
  for (int k = 0; k < 15; ++k) mid[k] = 0.5f * (cb[k] + cb[k + 1]);

  const int gid = blockIdx.x * blockDim.x + threadIdx.x;

  const f32x4* __restrict__ x4 = (const f32x4*)x;
  i32x4* __restrict__ o4 = (i32x4*)out;

  if (gid < n4) {
    f32x4 v = x4[gid];  // cached load — exploit L3-warm input
    int c0 = 0, c1 = 0, c2 = 0, c3 = 0;
#pragma unroll
    for (int k = 0; k < 15; ++k) {
      c0 += (v.x > mid[k]);
      c1 += (v.y > mid[k]);
      c2 += (v.z > mid[k]);
      c3 += (v.w > mid[k]);
    }
    i32x4 r;
    r.x = c0; r.y = c1; r.z = c2; r.w = c3;
    __builtin_nontemporal_store(r, o4 + gid);  // streaming store
  }

  // Scalar tail (n % 4) — n=15,360,000 is divisible by 4; kept for safety.
  const int total = gridDim.x * blockDim.x;
  for (int j = n4 * 4 + gid; j < n; j += total) {
    float v = x[j];
    int c = 0;
#pragma unroll
    for (int k = 0; k < 15; ++k) c += (v > mid[k]);
    out[j] = c;
  }
}

extern "C" void kernel_launch(void* const* d_in, const int* in_sizes, int n_in,
                              void* d_out, int out_size, void* d_ws, size_t ws_size,
                              hipStream_t stream) {
  const float* x = (const float*)d_in[0];
  const float* cb = (const float*)d_in[1];
  int* out = (int*)d_out;

  const int n = in_sizes[0];
  const int n4 = n / 4;

  const int block = 256;
  int grid = (n4 + block - 1) / block;  // 15000 for n=15,360,000 — one shot
  if (grid < 1) grid = 1;

  dmels_quant_kernel<<<grid, block, 0, stream>>>(x, cb, out, n4, n);
}